// Round 1
// baseline (2796.544 us; speedup 1.0000x reference)
//
#include <hip/hip_runtime.h>
#include <cfloat>

// Problem constants (match reference).
#define B_   16
#define P_   196
#define D_   768
#define N_   2048
#define K_   20
#define PS_  16
#define NR_  14
#define IMG_ 224   // NR_*PS_

// ---------------------------------------------------------------------------
// Kernel 1: sim[b,p,n] = sum_d test[b,p,d] * train[p,d,n], fp64 accumulate.
// grid = (P_, N_/512); block = 256 threads; each thread: 2 consecutive n, all 16 b.
// LDS: test patch A[16][768] fp32 (48 KB) -> 3 blocks/CU possible.
// ---------------------------------------------------------------------------
__global__ __launch_bounds__(256) void sim_kernel(
    const float* __restrict__ test,   // [B,P,D]
    const float* __restrict__ train,  // [P,D,N]
    double* __restrict__ sim)         // [B,P,N]
{
    __shared__ float As[B_ * D_];  // 48 KB
    const int p   = blockIdx.x;
    const int nc  = blockIdx.y;    // 0..3
    const int tid = threadIdx.x;

    // Stage A tile: A[b][d] = test[(b*P + p)*D + d]; rows are contiguous, D%4==0.
    for (int i = tid * 4; i < B_ * D_; i += 256 * 4) {
        const int b = i / D_;
        const int d = i - b * D_;
        const float4 v = *(const float4*)(test + ((size_t)b * P_ + p) * D_ + d);
        *(float4*)(As + i) = v;
    }
    __syncthreads();

    const int n0 = nc * 512 + tid * 2;
    const float* tp = train + (size_t)p * D_ * N_ + n0;

    double acc0[B_], acc1[B_];
    #pragma unroll
    for (int b = 0; b < B_; ++b) { acc0[b] = 0.0; acc1[b] = 0.0; }

    #pragma unroll 4
    for (int d = 0; d < D_; ++d) {
        const float2 t2 = *(const float2*)(tp + (size_t)d * N_);
        const double t0 = (double)t2.x;
        const double t1 = (double)t2.y;
        #pragma unroll
        for (int b = 0; b < B_; ++b) {
            const double a = (double)As[b * D_ + d];
            acc0[b] += a * t0;
            acc1[b] += a * t1;
        }
    }

    #pragma unroll
    for (int b = 0; b < B_; ++b) {
        const size_t o = ((size_t)b * P_ + p) * N_ + n0;
        sim[o]     = acc0[b];
        sim[o + 1] = acc1[b];
    }
}

// ---------------------------------------------------------------------------
// Kernel 2: top-K per row of sim (fp64). One block (256 thr) per (b,p) row.
// Iterative argmax x K with LDS tree reduction; ties -> lowest index
// (matches stable descending sort semantics of top_k).
// ---------------------------------------------------------------------------
__global__ __launch_bounds__(256) void topk_kernel(
    const double* __restrict__ sim,  // [B*P, N]
    float* __restrict__ dist,        // [B*P, K]
    int* __restrict__ idxout)        // [B*P, K]
{
    const int row = blockIdx.x;
    const int tid = threadIdx.x;
    __shared__ double sval[256];
    __shared__ int    sidx[256];

    double v[8];
    const double* rp = sim + (size_t)row * N_;
    #pragma unroll
    for (int j = 0; j < 8; ++j) v[j] = rp[tid + 256 * j];

    for (int it = 0; it < K_; ++it) {
        // local argmax over this thread's 8 slots (lowest n on ties)
        double best = -DBL_MAX;
        int    bidx = N_;
        #pragma unroll
        for (int j = 0; j < 8; ++j) {
            const int n = tid + 256 * j;
            if (v[j] > best || (v[j] == best && n < bidx)) { best = v[j]; bidx = n; }
        }
        sval[tid] = best;
        sidx[tid] = bidx;
        __syncthreads();
        for (int s = 128; s > 0; s >>= 1) {
            if (tid < s) {
                const double ov = sval[tid + s];
                const int    oi = sidx[tid + s];
                if (ov > sval[tid] || (ov == sval[tid] && oi < sidx[tid])) {
                    sval[tid] = ov; sidx[tid] = oi;
                }
            }
            __syncthreads();
        }
        const double wv = sval[0];
        const int    wi = sidx[0];
        if (tid == 0) {
            dist[(size_t)row * K_ + it]   = (float)wv;
            idxout[(size_t)row * K_ + it] = wi;
        }
        // invalidate winner (static indices to keep v[] in registers)
        #pragma unroll
        for (int j = 0; j < 8; ++j) {
            if (wi == tid + 256 * j) v[j] = -DBL_MAX;
        }
        __syncthreads();
    }
}

// ---------------------------------------------------------------------------
// Kernel 3: grid[b,k,y,x] = labels[p=(y/16)*14+(x/16), s=(y%16)*16+(x%16), idx[b,p,k]]
// One thread per output pixel; writes coalesced; gathered reads hit L2.
// ---------------------------------------------------------------------------
__global__ __launch_bounds__(256) void grid_kernel(
    const int* __restrict__ labels,  // [P, 256, N]
    const int* __restrict__ idxin,   // [B, P, K]
    float* __restrict__ out)         // [B, K, 224, 224]
{
    const size_t o = (size_t)blockIdx.x * 256 + threadIdx.x;
    const int x = (int)(o % IMG_);
    size_t t = o / IMG_;
    const int y = (int)(t % IMG_);
    t /= IMG_;
    const int k = (int)(t % K_);
    const int b = (int)(t / K_);

    const int p = (y >> 4) * NR_ + (x >> 4);
    const int s = ((y & 15) << 4) | (x & 15);
    const int n = idxin[((size_t)b * P_ + p) * K_ + k];
    const int lab = labels[((size_t)p * 256 + s) * N_ + n];
    out[o] = (float)lab;
}

// ---------------------------------------------------------------------------
extern "C" void kernel_launch(void* const* d_in, const int* in_sizes, int n_in,
                              void* d_out, int out_size, void* d_ws, size_t ws_size,
                              hipStream_t stream) {
    const float* test   = (const float*)d_in[0];  // [B,P,D] fp32
    const float* train  = (const float*)d_in[1];  // [P,D,N] fp32
    const int*   labels = (const int*)d_in[2];    // [P,256,N] int32

    float* out  = (float*)d_out;
    float* dist = out;                        // [B,P,K]
    float* grid = out + (size_t)B_ * P_ * K_; // [B,K,224,224]

    double* sim  = (double*)d_ws;                                   // 51.4 MB
    int*    idxw = (int*)((char*)d_ws + (size_t)B_ * P_ * N_ * sizeof(double));

    dim3 g1(P_, N_ / 512);
    sim_kernel<<<g1, 256, 0, stream>>>(test, train, sim);
    topk_kernel<<<B_ * P_, 256, 0, stream>>>(sim, dist, idxw);

    const int npix = B_ * K_ * IMG_ * IMG_;   // 16,056,320
    grid_kernel<<<npix / 256, 256, 0, stream>>>(labels, idxw, grid);
}